// Round 1
// baseline (1765.480 us; speedup 1.0000x reference)
//
#include <hip/hip_runtime.h>
#include <hip/hip_bf16.h>
#include <stdint.h>

// ---------------- problem constants ----------------
#define NB      128          // batch
#define NH      101          // AH+1 = VH+1 = TH+1
#define NIN     300          // input dims
#define NP      300          // POST_DIM
#define NO      300          // OUT_DIM
#define K_TOT   1030301      // 101^3
#define NAV     10201        // 101^2
#define CHUNK   32
#define NCHUNKS ((K_TOT + CHUNK - 1) / CHUNK)   // 32197
#define RANGES_DEFAULT 153
#define PTILES  5
#define PPAD    320
#define ASTRIDE 40           // bf16 elems per row in Al/Wl (80B: 16B-aligned frags, <=2-way banks)
#define TSTRIDE 102          // bf16 elems per row of T in LDS/ws

typedef __attribute__((ext_vector_type(8))) short bf16x8;
typedef __attribute__((ext_vector_type(4))) float f32x4;

static __device__ __forceinline__ unsigned short f2bf(float f) {
    union { float f; unsigned u; } x; x.f = f;
    unsigned r = x.u + 0x7fffu + ((x.u >> 16) & 1u);   // RNE
    return (unsigned short)(r >> 16);
}
static __device__ __forceinline__ float bf2f(unsigned short h) {
    union { unsigned u; float f; } x; x.u = ((unsigned)h) << 16;
    return x.f;
}

// ---------------- K1: three projections ----------------
// Af/Vf/Tf: [128][101] fp32, col 0 = 1.0, col 1+i = x@W.T + bias
__global__ __launch_bounds__(256) void proj_kernel(
    const float* __restrict__ ax, const float* __restrict__ vx, const float* __restrict__ tx,
    const float* __restrict__ Wa, const float* __restrict__ ba,
    const float* __restrict__ Wv, const float* __restrict__ bv,
    const float* __restrict__ Wt, const float* __restrict__ bt,
    float* __restrict__ Af, float* __restrict__ Vf, float* __restrict__ Tf)
{
    int g = blockIdx.x * 256 + threadIdx.x;
    if (g >= 3 * NB * NH) return;
    int mod = g / (NB * NH);
    int rem = g - mod * (NB * NH);
    int b = rem / NH, j = rem - b * NH;
    const float* x = (mod == 0) ? ax : (mod == 1) ? vx : tx;
    const float* W = (mod == 0) ? Wa : (mod == 1) ? Wv : Wt;
    const float* bi = (mod == 0) ? ba : (mod == 1) ? bv : bt;
    float val;
    if (j == 0) {
        val = 1.0f;
    } else {
        const float4* xr = (const float4*)(x + (size_t)b * NIN);
        const float4* wr = (const float4*)(W + (size_t)(j - 1) * NIN);
        float s0 = 0.f, s1 = 0.f, s2 = 0.f, s3 = 0.f;
        #pragma unroll 5
        for (int i = 0; i < NIN / 4; ++i) {
            float4 a = xr[i], w = wr[i];
            s0 += a.x * w.x; s1 += a.y * w.y; s2 += a.z * w.z; s3 += a.w * w.w;
        }
        val = (s0 + s1) + (s2 + s3) + bi[j - 1];
    }
    float* dst = (mod == 0) ? Af : (mod == 1) ? Vf : Tf;
    dst[b * NH + j] = val;
}

// ---------------- K2: AVbf (av-major, transposed) + Tbf ----------------
// AVbf[av][b] bf16, Tbf[b][TSTRIDE] bf16
__global__ __launch_bounds__(256) void av_kernel(
    const float* __restrict__ Af, const float* __restrict__ Vf, const float* __restrict__ Tf,
    unsigned short* __restrict__ AVbf, unsigned short* __restrict__ Tbf)
{
    int g = blockIdx.x * 256 + threadIdx.x;
    if (g < NB * TSTRIDE) {
        int b = g / TSTRIDE, j = g - b * TSTRIDE;
        Tbf[g] = (j < NH) ? f2bf(Tf[b * NH + j]) : (unsigned short)0;
    }
    if (g < NAV * NB) {
        int av = g >> 7, b = g & 127;
        int a = av / NH, v = av - a * NH;
        AVbf[g] = f2bf(Af[b * NH + a] * Vf[b * NH + v]);
    }
}

// ---------------- K3: the big fused fusion-GEMM ----------------
// grid (PTILES, R). wg: 256 thr / 4 waves. Per chunk (32 k):
//   stage Al[128][32] bf16 fusion tile (from AVbf regs * Tl LDS) and
//   Wl[64][32] bf16 W1 tile (coalesced fp32 global loads, prefetched), then
//   each wave: 8x mfma_f32_16x16x32_bf16 (8 b-tiles x its 16-p subtile).
// Writes partial[rng][128][PPAD].
__global__ __launch_bounds__(256) void fusion_gemm_kernel(
    const float* __restrict__ W1, const unsigned short* __restrict__ AVbf,
    const unsigned short* __restrict__ Tbf, float* __restrict__ partial, int cpr)
{
    __shared__ unsigned short Tl[NB * TSTRIDE];   // 26112 B
    __shared__ unsigned short Al[NB * ASTRIDE];   // 10240 B
    __shared__ unsigned short Wl[64 * ASTRIDE];   //  5120 B

    const int tid   = threadIdx.x;
    const int ptile = blockIdx.x;
    const int rng   = blockIdx.y;
    const int wave  = tid >> 6;
    const int lane  = tid & 63;
    const int ln15  = lane & 15;
    const int quad  = lane >> 4;

    // cooperative T copy (dwords)
    {
        const unsigned* src = (const unsigned*)Tbf;
        unsigned* dst = (unsigned*)Tl;
        for (int i = tid; i < NB * TSTRIDE / 2; i += 256) dst[i] = src[i];
    }

    const int c0 = rng * cpr;
    const int c1 = min(c0 + cpr, NCHUNKS);

    // staging mapping
    const int kk   = tid & 31;          // k within chunk
    const int bg   = (tid >> 5) << 4;   // batch group base (16 b per group)
    const int wrow = tid >> 5;          // W-staging row base (0..7)

    f32x4 acc[8];
    #pragma unroll
    for (int i = 0; i < 8; ++i) acc[i] = (f32x4){0.f, 0.f, 0.f, 0.f};

    float    wreg[8];
    unsigned avp[8];
    unsigned tt = 0;
    bool     valid = true;

    __syncthreads();   // Tl ready before first stage

    // prefetch issue for chunk c: W1 slice + AV slice into registers
    auto issue_loads = [&](int c) {
        unsigned kg = (unsigned)c * CHUNK + (unsigned)kk;
        valid = (kg < K_TOT);
        unsigned kc = valid ? kg : (unsigned)(K_TOT - 1);
        #pragma unroll
        for (int it = 0; it < 8; ++it) {
            int pr = ptile * 64 + wrow + it * 8;
            if (pr > NP - 1) pr = NP - 1;
            wreg[it] = W1[(size_t)pr * K_TOT + kc];
        }
        unsigned av = kc / 101u;
        tt = kc - av * 101u;
        const unsigned* avsrc = (const unsigned*)(AVbf + (size_t)av * NB + bg);
        #pragma unroll
        for (int j = 0; j < 8; ++j) avp[j] = avsrc[j];
    };

    if (c0 < c1) issue_loads(c0);

    for (int c = c0; c < c1; ++c) {
        // ---- stage W(c): regs -> bf16 LDS ----
        #pragma unroll
        for (int it = 0; it < 8; ++it)
            Wl[(wrow + it * 8) * ASTRIDE + kk] = f2bf(wreg[it]);
        // ---- stage A(c): AV * T -> bf16 LDS ----
        #pragma unroll
        for (int j2 = 0; j2 < 8; ++j2) {
            unsigned pk = avp[j2];
            int b0 = bg + j2 * 2;
            float a0 = bf2f((unsigned short)(pk & 0xffffu));
            float a1 = bf2f((unsigned short)(pk >> 16));
            float t0 = bf2f(Tl[b0 * TSTRIDE + tt]);
            float t1 = bf2f(Tl[(b0 + 1) * TSTRIDE + tt]);
            Al[b0 * ASTRIDE + kk]       = valid ? f2bf(a0 * t0) : (unsigned short)0;
            Al[(b0 + 1) * ASTRIDE + kk] = valid ? f2bf(a1 * t1) : (unsigned short)0;
        }
        __syncthreads();
        if (c + 1 < c1) issue_loads(c + 1);   // overlap next chunk's HBM latency with MFMA
        // ---- compute ----
        bf16x8 bfrag = *(const bf16x8*)&Wl[(wave * 16 + ln15) * ASTRIDE + quad * 8];
        #pragma unroll
        for (int bt = 0; bt < 8; ++bt) {
            bf16x8 afrag = *(const bf16x8*)&Al[(bt * 16 + ln15) * ASTRIDE + quad * 8];
            acc[bt] = __builtin_amdgcn_mfma_f32_16x16x32_bf16(afrag, bfrag, acc[bt], 0, 0, 0);
        }
        __syncthreads();
    }

    // epilogue: D layout col=lane&15 (p), row=quad*4+reg (b)
    const int p = ptile * 64 + wave * 16 + ln15;
    #pragma unroll
    for (int bt = 0; bt < 8; ++bt) {
        #pragma unroll
        for (int rg = 0; rg < 4; ++rg) {
            int b = bt * 16 + quad * 4 + rg;
            partial[((size_t)rng * NB + b) * PPAD + p] = acc[bt][rg];
        }
    }
}

// ---------------- K4: reduce partials + bias + relu -> h ----------------
__global__ __launch_bounds__(256) void reduce_kernel(
    const float* __restrict__ partial, const float* __restrict__ b1,
    float* __restrict__ h, int R)
{
    int g = blockIdx.x * 256 + threadIdx.x;
    if (g >= NB * NP) return;
    int b = g / NP, p = g - b * NP;
    float s = b1[p];
    const float* src = partial + (size_t)b * PPAD + p;
    for (int r = 0; r < R; ++r) s += src[(size_t)r * NB * PPAD];
    h[b * NP + p] = fmaxf(s, 0.f);
}

// ---------------- K5: second GEMM + relu -> out ----------------
__global__ __launch_bounds__(256) void gemm2_kernel(
    const float* __restrict__ h, const float* __restrict__ W2,
    const float* __restrict__ b2, float* __restrict__ out)
{
    int g = blockIdx.x * 256 + threadIdx.x;
    if (g >= NB * NO) return;
    int b = g / NO, o = g - b * NO;
    const float4* hr = (const float4*)(h + (size_t)b * NP);
    const float4* wr = (const float4*)(W2 + (size_t)o * NP);
    float s0 = 0.f, s1 = 0.f, s2 = 0.f, s3 = 0.f;
    #pragma unroll 5
    for (int i = 0; i < NP / 4; ++i) {
        float4 a = hr[i], w = wr[i];
        s0 += a.x * w.x; s1 += a.y * w.y; s2 += a.z * w.z; s3 += a.w * w.w;
    }
    out[g] = fmaxf((s0 + s1) + (s2 + s3) + b2[o], 0.f);
}

// ---------------- host launch ----------------
extern "C" void kernel_launch(void* const* d_in, const int* in_sizes, int n_in,
                              void* d_out, int out_size, void* d_ws, size_t ws_size,
                              hipStream_t stream) {
    const float* ax = (const float*)d_in[0];
    const float* vx = (const float*)d_in[1];
    const float* tx = (const float*)d_in[2];
    const float* Wa = (const float*)d_in[3];
    const float* ba = (const float*)d_in[4];
    const float* Wv = (const float*)d_in[5];
    const float* bv = (const float*)d_in[6];
    const float* Wt = (const float*)d_in[7];
    const float* bt = (const float*)d_in[8];
    const float* W1 = (const float*)d_in[9];
    const float* b1 = (const float*)d_in[10];
    const float* W2 = (const float*)d_in[11];
    const float* b2 = (const float*)d_in[12];
    float* out = (float*)d_out;

    // ws layout (bytes)
    char* ws = (char*)d_ws;
    size_t off = 0;
    float* Af = (float*)(ws + off); off += (size_t)NB * NH * 4;        // 51712
    float* Vf = (float*)(ws + off); off += (size_t)NB * NH * 4;        // 51712
    float* Tf = (float*)(ws + off); off += (size_t)NB * NH * 4;        // 51712
    float* h  = (float*)(ws + off); off += (size_t)NB * NP * 4;        // 153600
    unsigned short* Tbf  = (unsigned short*)(ws + off); off += (size_t)NB * TSTRIDE * 2;  // 26112
    unsigned short* AVbf = (unsigned short*)(ws + off); off += (size_t)NAV * NB * 2;      // 2611456
    size_t fixed = off;
    const size_t per_range = (size_t)NB * PPAD * 4;   // 163840
    int R = RANGES_DEFAULT;
    if (ws_size < fixed + (size_t)R * per_range) {
        size_t avail = (ws_size > fixed) ? (ws_size - fixed) : per_range;
        R = (int)(avail / per_range);
        if (R < 1) R = 1;
    }
    float* partial = (float*)(ws + fixed);
    int cpr = (NCHUNKS + R - 1) / R;

    proj_kernel<<<(3 * NB * NH + 255) / 256, 256, 0, stream>>>(
        ax, vx, tx, Wa, ba, Wv, bv, Wt, bt, Af, Vf, Tf);
    av_kernel<<<(NAV * NB + 255) / 256, 256, 0, stream>>>(Af, Vf, Tf, AVbf, Tbf);
    fusion_gemm_kernel<<<dim3(PTILES, R), 256, 0, stream>>>(W1, AVbf, Tbf, partial, cpr);
    reduce_kernel<<<(NB * NP + 255) / 256, 256, 0, stream>>>(partial, b1, h, R);
    gemm2_kernel<<<(NB * NO + 255) / 256, 256, 0, stream>>>(h, W2, b2, out);
}